// Round 4
// baseline (221.827 us; speedup 1.0000x reference)
//
#include <hip/hip_runtime.h>
#include <hip/hip_bf16.h>
#include <math.h>

#define Bsz 2
#define Tseq 2048
#define Cdim 1024
#define Hn 16
#define HDim 64
#define Mrows 4096
#define N3 3072
#define QSCALE 0.1803368801111137f   /* 0.125 * log2(e) baked into Q */

typedef __bf16 bf16_t;
typedef __bf16 bf16x4 __attribute__((ext_vector_type(4)));
typedef __bf16 bf16x8 __attribute__((ext_vector_type(8)));
typedef _Float16 f16x4 __attribute__((ext_vector_type(4)));
typedef _Float16 f16x8 __attribute__((ext_vector_type(8)));
typedef float floatx4 __attribute__((ext_vector_type(4)));

__device__ __forceinline__ void async16(const void* g, void* l) {
    __builtin_amdgcn_global_load_lds(
        (const __attribute__((address_space(1))) void*)g,
        (__attribute__((address_space(3))) void*)l, 16, 0, 0);
}

// ---------------------------------------------------------------------------
// fp32 -> bf16 convert (x), 8 elems/thread
// ---------------------------------------------------------------------------
__global__ __launch_bounds__(256) void convert_kernel(
    const float* __restrict__ in, bf16_t* __restrict__ out)
{
    size_t g = (size_t)blockIdx.x * 256 + threadIdx.x;
    float4 a = *(const float4*)(in + g * 8);
    float4 b = *(const float4*)(in + g * 8 + 4);
    bf16x8 o;
    o[0] = (bf16_t)a.x; o[1] = (bf16_t)a.y; o[2] = (bf16_t)a.z; o[3] = (bf16_t)a.w;
    o[4] = (bf16_t)b.x; o[5] = (bf16_t)b.y; o[6] = (bf16_t)b.z; o[7] = (bf16_t)b.w;
    *(bf16x8*)(out + g * 8) = o;
}

// ---------------------------------------------------------------------------
// fp32 (R,C) -> bf16 (C,R) transpose-convert, 32x32 tiles
// ---------------------------------------------------------------------------
__global__ __launch_bounds__(256) void transpose_kernel(
    const float* __restrict__ in, bf16_t* __restrict__ out, int R, int C)
{
    __shared__ float Ts[32][33];
    int c0 = blockIdx.x << 5, r0 = blockIdx.y << 5;
    int lr = threadIdx.x >> 3, lc = (threadIdx.x & 7) << 2;
    float4 v = *(const float4*)(in + (size_t)(r0 + lr) * C + c0 + lc);
    Ts[lr][lc] = v.x; Ts[lr][lc + 1] = v.y; Ts[lr][lc + 2] = v.z; Ts[lr][lc + 3] = v.w;
    __syncthreads();
    bf16x4 o;
    o[0] = (bf16_t)Ts[lc + 0][lr]; o[1] = (bf16_t)Ts[lc + 1][lr];
    o[2] = (bf16_t)Ts[lc + 2][lr]; o[3] = (bf16_t)Ts[lc + 3][lr];
    *(bf16x4*)(out + (size_t)(c0 + lr) * R + r0 + lc) = o;
}

// ---------------------------------------------------------------------------
// QKV GEMM (m97 structure) + fused bias + rotary(q,k) + Q pre-scale.
// q,k -> bf16 (BH,T,HD); v -> f16 (BH,HD,T) with key-permuted T (sigma baked
// in so attn's PV can use 16x16x32_f16 MFMA straight from P registers).
// ---------------------------------------------------------------------------
__global__ __launch_bounds__(256) void gemm_qkv(
    const bf16_t* __restrict__ xb, const bf16_t* __restrict__ waT,
    const float* __restrict__ bias, const float* __restrict__ cosb,
    const float* __restrict__ sinb,
    bf16_t* __restrict__ qb, bf16_t* __restrict__ kb, _Float16* __restrict__ vt)
{
    __shared__ bf16_t As[128 * 32];
    __shared__ bf16_t Bs[128 * 32];
    const int tid = threadIdx.x;
    const int lane = tid & 63, w = tid >> 6;
    const int lm = lane & 15, quad = lane >> 4;
    const int wy = w >> 1, wx = w & 1;
    const int m0 = blockIdx.y << 7, n0 = blockIdx.x << 7;

    const floatx4 fz = {0.f, 0.f, 0.f, 0.f};
    floatx4 acc[4][4];
    #pragma unroll
    for (int i = 0; i < 4; i++)
        #pragma unroll
        for (int j = 0; j < 4; j++) acc[i][j] = fz;

    const bf16_t* Ag = xb + (size_t)m0 * Cdim;
    const bf16_t* Bg = waT + (size_t)n0 * Cdim;

    for (int k0 = 0; k0 < Cdim; k0 += 32) {
        #pragma unroll
        for (int it = 0; it < 2; ++it) {
            int ci = (w << 7) + (it << 6) + lane;
            int row = ci >> 2, cq = (ci & 3) ^ (row & 3);
            async16(Ag + (size_t)row * Cdim + k0 + cq * 8, As + ((w << 7) + (it << 6)) * 8);
            async16(Bg + (size_t)row * Cdim + k0 + cq * 8, Bs + ((w << 7) + (it << 6)) * 8);
        }
        __syncthreads();
        bf16x8 af[4], bfr[4];
        #pragma unroll
        for (int i = 0; i < 4; i++) {
            int row = (wy << 6) + (i << 4) + lm;
            int cq = quad ^ (lm & 3);
            af[i] = *(const bf16x8*)&As[row * 32 + cq * 8];
        }
        #pragma unroll
        for (int j = 0; j < 4; j++) {
            int row = (wx << 6) + (j << 4) + lm;
            int cq = quad ^ (lm & 3);
            bfr[j] = *(const bf16x8*)&Bs[row * 32 + cq * 8];
        }
        #pragma unroll
        for (int i = 0; i < 4; i++)
            #pragma unroll
            for (int j = 0; j < 4; j++)
                acc[i][j] = __builtin_amdgcn_mfma_f32_16x16x32_bf16(af[i], bfr[j], acc[i][j], 0, 0, 0);
        __syncthreads();
    }

    // epilogue: C/D layout col=lane&15, row=quad*4+reg
    const int sec = n0 >> 10;                 // block-uniform: 0=q 1=k 2=v
    const int mb = m0 + (wy << 6);
    const int nb = n0 + (wx << 6);
    #pragma unroll
    for (int i = 0; i < 4; i++) {
        int mrow0 = mb + (i << 4) + (quad << 2);
        int b = mrow0 >> 11, t0 = mrow0 & 2047;
        #pragma unroll
        for (int j = 0; j < 4; j++) {
            int n = nb + (j << 4) + lm;
            float bi = bias[n];
            int rel = n & 1023;
            int h = rel >> 6, hd = rel & 63;
            if (sec == 2) {
                f16x4 pk;
                #pragma unroll
                for (int r = 0; r < 4; r++) pk[r] = (_Float16)(acc[i][j][r] + bi);
                // sigma: physical key t0 -> permuted slot within its 32-group
                int tp = (t0 & ~31) | (((t0 >> 2) & 3) << 3) | (((t0 >> 4) & 1) << 2);
                *(f16x4*)&vt[((size_t)(b * Hn + h) * HDim + hd) * Tseq + tp] = pk;
            } else {
                bf16_t* dst = (sec == 0) ? qb : kb;
                const int ih = hd >> 1;
                const bool ev = !(hd & 1);
                #pragma unroll
                for (int r = 0; r < 4; r++) {
                    int t = t0 + r;
                    float v = acc[i][j][r] + bi;
                    float x = __shfl_xor(v, 1);        // rotary pair partner
                    float c = cosb[t * 32 + ih], s = sinb[t * 32 + ih];
                    float rv = ev ? (v * c - x * s) : (x * s + v * c);
                    if (sec == 0) rv *= QSCALE;
                    dst[((size_t)(b * Hn + h) * Tseq + t) * HDim + hd] = (bf16_t)rv;
                }
            }
        }
    }
}

// ---------------------------------------------------------------------------
// Flash attention. 512 blocks x 256 threads. Block = (bh, pair pp): 64-row
// q-tiles (pp, 31-pp); each wave owns 16 q-rows of BOTH tiles. Single kt
// loop 0..31-pp: heavy tile always active, light while kt<=pp (prefix), so
// K/V fragments are shared and every wave computes every iteration -> 33
// units/block, perfectly balanced. S^T = K*Q^T (bf16 x32); softmax per-lane
// + 2 shuffles; PV = V^T P^T via f16 x32 with the key permutation baked
// into vt. One barrier per k-tile, double-buffered K/V.
// ---------------------------------------------------------------------------
__global__ __launch_bounds__(256) void attn_mfma(
    const bf16_t* __restrict__ qb, const bf16_t* __restrict__ kb,
    const _Float16* __restrict__ vt, bf16_t* __restrict__ yb)
{
    __shared__ bf16_t Qs[2][64 * 64];       // 16 KB (both q-tiles)
    __shared__ bf16_t Ks[2][64 * 64];       // 16 KB dbuf
    __shared__ _Float16 VTs[2][64 * 64];    // 16 KB dbuf

    const int pp = blockIdx.x & 15;
    const int bh = blockIdx.x >> 4;
    const int b = bh >> 4, h = bh & 15;
    const int tid = threadIdx.x;
    const int w4 = tid >> 6, lane = tid & 63, lm = lane & 15, quad = lane >> 4;
    const int jt0 = pp, jt1 = 31 - pp;
    const int nk = 32 - pp;                  // kt = 0 .. nk-1

    // stage both Q tiles + K/V tile 0
    #pragma unroll
    for (int t = 0; t < 2; ++t) {
        const bf16_t* Qg = qb + ((size_t)bh * Tseq + ((t ? jt1 : jt0) << 6)) * HDim;
        #pragma unroll
        for (int it = 0; it < 2; ++it) {
            int ci = (it << 8) + tid;
            int row = ci >> 3, cq = (ci & 7) ^ (row & 7);
            async16(Qg + row * HDim + cq * 8, &Qs[t][((it << 8) + (w4 << 6)) * 8]);
        }
    }
    {
        const bf16_t* Kg = kb + (size_t)bh * Tseq * HDim;
        const _Float16* Vg = vt + (size_t)bh * HDim * Tseq;
        #pragma unroll
        for (int it = 0; it < 2; ++it) {
            int ci = (it << 8) + tid;
            int row = ci >> 3, cq = (ci & 7) ^ (row & 7);
            async16(Kg + row * HDim + cq * 8, &Ks[0][((it << 8) + (w4 << 6)) * 8]);
            async16(Vg + (size_t)row * Tseq + cq * 8, &VTs[0][((it << 8) + (w4 << 6)) * 8]);
        }
    }
    __syncthreads();

    // loop-invariant Q fragments (B-operand x32: n=lm, k=quad*8+j)
    bf16x8 qf[2][2];
    #pragma unroll
    for (int t = 0; t < 2; ++t)
        #pragma unroll
        for (int ks = 0; ks < 2; ++ks) {
            int qrow = (w4 << 4) + lm;
            int qc = ((ks << 2) + quad) ^ (qrow & 7);
            qf[t][ks] = *(const bf16x8*)&Qs[t][qrow * 64 + qc * 8];
        }

    const floatx4 fz = {0.f, 0.f, 0.f, 0.f};
    floatx4 o_[2][4];                        // O^T: [tile][d-subtile]
    #pragma unroll
    for (int t = 0; t < 2; ++t)
        #pragma unroll
        for (int f = 0; f < 4; ++f) o_[t][f] = fz;
    float m_[2] = {-3e38f, -3e38f}, l_[2] = {0.f, 0.f};
    const int lastk[2] = {pp, 31 - pp};
    const int qq[2] = {(jt0 << 6) + (w4 << 4) + lm, (jt1 << 6) + (w4 << 4) + lm};

    for (int kt = 0; kt < nk; ++kt) {
        const int cb = kt & 1;
        if (kt + 1 < nk) {                    // prefetch next K/V tile
            const int nb2 = cb ^ 1;
            const bf16_t* Kg = kb + ((size_t)bh * Tseq + ((kt + 1) << 6)) * HDim;
            const _Float16* Vg = vt + (size_t)bh * HDim * Tseq + ((kt + 1) << 6);
            #pragma unroll
            for (int it = 0; it < 2; ++it) {
                int ci = (it << 8) + tid;
                int row = ci >> 3, cq = (ci & 7) ^ (row & 7);
                async16(Kg + row * HDim + cq * 8, &Ks[nb2][((it << 8) + (w4 << 6)) * 8]);
                async16(Vg + (size_t)row * Tseq + cq * 8, &VTs[nb2][((it << 8) + (w4 << 6)) * 8]);
            }
        }

        // S^T = K Q^T for both tiles (K-fragments shared)
        floatx4 st[2][4];
        #pragma unroll
        for (int t = 0; t < 2; ++t)
            #pragma unroll
            for (int sub = 0; sub < 4; ++sub) st[t][sub] = fz;
        #pragma unroll
        for (int ks = 0; ks < 2; ++ks) {
            bf16x8 kf[4];
            #pragma unroll
            for (int sub = 0; sub < 4; ++sub) {
                int krow = (sub << 4) + lm;
                int kc = ((ks << 2) + quad) ^ (krow & 7);
                kf[sub] = *(const bf16x8*)&Ks[cb][krow * 64 + kc * 8];
            }
            if (kt <= lastk[0])
                #pragma unroll
                for (int sub = 0; sub < 4; ++sub)
                    st[0][sub] = __builtin_amdgcn_mfma_f32_16x16x32_bf16(
                        kf[sub], qf[0][ks], st[0][sub], 0, 0, 0);
            #pragma unroll
            for (int sub = 0; sub < 4; ++sub)
                st[1][sub] = __builtin_amdgcn_mfma_f32_16x16x32_bf16(
                    kf[sub], qf[1][ks], st[1][sub], 0, 0, 0);
        }

        // online softmax per tile (lane covers 16 keys of q-column lm)
        #pragma unroll
        for (int t = 0; t < 2; ++t) {
            if (kt > lastk[t]) continue;
            const bool dm = (kt == lastk[t]);
            float mx = -3e38f;
            #pragma unroll
            for (int sub = 0; sub < 4; ++sub)
                #pragma unroll
                for (int r = 0; r < 4; ++r) {
                    float val = st[t][sub][r];
                    if (dm) {
                        int key = (kt << 6) + (sub << 4) + (quad << 2) + r;
                        if (key > qq[t]) val = -3e38f;
                    }
                    st[t][sub][r] = val;
                    mx = fmaxf(mx, val);
                }
            mx = fmaxf(mx, __shfl_xor(mx, 16));
            mx = fmaxf(mx, __shfl_xor(mx, 32));
            float mnew = fmaxf(m_[t], mx);
            float alpha = exp2f(m_[t] - mnew);
            float rs = 0.f;
            #pragma unroll
            for (int sub = 0; sub < 4; ++sub)
                #pragma unroll
                for (int r = 0; r < 4; ++r) {
                    float pv = exp2f(st[t][sub][r] - mnew);
                    st[t][sub][r] = pv;
                    rs += pv;
                }
            rs += __shfl_xor(rs, 16);
            rs += __shfl_xor(rs, 32);
            m_[t] = mnew;
            l_[t] = l_[t] * alpha + rs;
            #pragma unroll
            for (int f = 0; f < 4; ++f) o_[t][f] *= alpha;
        }

        // O^T += V^T P^T (f16 x32; V-fragments shared across tiles)
        #pragma unroll
        for (int cc = 0; cc < 2; ++cc) {
            f16x8 vf[4];
            #pragma unroll
            for (int f = 0; f < 4; ++f) {
                int vrow = (f << 4) + lm;
                int vc = ((cc << 2) + quad) ^ (vrow & 7);
                vf[f] = *(const f16x8*)&VTs[cb][vrow * 64 + vc * 8];
            }
            #pragma unroll
            for (int t = 0; t < 2; ++t) {
                if (kt > lastk[t]) continue;
                f16x8 pf;
                #pragma unroll
                for (int jj = 0; jj < 8; ++jj)
                    pf[jj] = (_Float16)st[t][(cc << 1) + (jj >> 2)][jj & 3];
                #pragma unroll
                for (int f = 0; f < 4; ++f)
                    o_[t][f] = __builtin_amdgcn_mfma_f32_16x16x32_f16(
                        vf[f], pf, o_[t][f], 0, 0, 0);
            }
        }
        __syncthreads();
    }

    // epilogue: O^T lane holds q=qq[t], d = f*16+quad*4+r
    #pragma unroll
    for (int t = 0; t < 2; ++t) {
        float inv = 1.f / l_[t];
        size_t base = ((size_t)(b * Tseq) + qq[t]) * Cdim + (h << 6) + (quad << 2);
        #pragma unroll
        for (int f = 0; f < 4; ++f) {
            bf16x4 ov;
            #pragma unroll
            for (int r = 0; r < 4; ++r) ov[r] = (bf16_t)(o_[t][f][r] * inv);
            *(bf16x4*)&yb[base + (f << 4)] = ov;
        }
    }
}

// ---------------------------------------------------------------------------
// Proj GEMM: (4096x1024) @ (1024x1024) + bias -> fp32 out.
// ---------------------------------------------------------------------------
__global__ __launch_bounds__(256) void gemm_proj(
    const bf16_t* __restrict__ yb, const bf16_t* __restrict__ wpT,
    const float* __restrict__ bias, float* __restrict__ out)
{
    __shared__ bf16_t As[128 * 32];
    __shared__ bf16_t Bs[128 * 32];
    const int tid = threadIdx.x;
    const int lane = tid & 63, w = tid >> 6;
    const int lm = lane & 15, quad = lane >> 4;
    const int wy = w >> 1, wx = w & 1;
    const int m0 = blockIdx.y << 7, n0 = blockIdx.x << 7;

    const floatx4 fz = {0.f, 0.f, 0.f, 0.f};
    floatx4 acc[4][4];
    #pragma unroll
    for (int i = 0; i < 4; i++)
        #pragma unroll
        for (int j = 0; j < 4; j++) acc[i][j] = fz;

    const bf16_t* Ag = yb + (size_t)m0 * Cdim;
    const bf16_t* Bg = wpT + (size_t)n0 * Cdim;

    for (int k0 = 0; k0 < Cdim; k0 += 32) {
        #pragma unroll
        for (int it = 0; it < 2; ++it) {
            int ci = (w << 7) + (it << 6) + lane;
            int row = ci >> 2, cq = (ci & 3) ^ (row & 3);
            async16(Ag + (size_t)row * Cdim + k0 + cq * 8, As + ((w << 7) + (it << 6)) * 8);
            async16(Bg + (size_t)row * Cdim + k0 + cq * 8, Bs + ((w << 7) + (it << 6)) * 8);
        }
        __syncthreads();
        bf16x8 af[4], bfr[4];
        #pragma unroll
        for (int i = 0; i < 4; i++) {
            int row = (wy << 6) + (i << 4) + lm;
            int cq = quad ^ (lm & 3);
            af[i] = *(const bf16x8*)&As[row * 32 + cq * 8];
        }
        #pragma unroll
        for (int j = 0; j < 4; j++) {
            int row = (wx << 6) + (j << 4) + lm;
            int cq = quad ^ (lm & 3);
            bfr[j] = *(const bf16x8*)&Bs[row * 32 + cq * 8];
        }
        #pragma unroll
        for (int i = 0; i < 4; i++)
            #pragma unroll
            for (int j = 0; j < 4; j++)
                acc[i][j] = __builtin_amdgcn_mfma_f32_16x16x32_bf16(af[i], bfr[j], acc[i][j], 0, 0, 0);
        __syncthreads();
    }

    const int mb = m0 + (wy << 6);
    const int nb = n0 + (wx << 6);
    #pragma unroll
    for (int i = 0; i < 4; i++) {
        int mrow0 = mb + (i << 4) + (quad << 2);
        #pragma unroll
        for (int j = 0; j < 4; j++) {
            int n = nb + (j << 4) + lm;
            float bi = bias[n];
            #pragma unroll
            for (int r = 0; r < 4; r++)
                out[(size_t)(mrow0 + r) * Cdim + n] = acc[i][j][r] + bi;
        }
    }
}

extern "C" void kernel_launch(void* const* d_in, const int* in_sizes, int n_in,
                              void* d_out, int out_size, void* d_ws, size_t ws_size,
                              hipStream_t stream) {
    const float* x      = (const float*)d_in[0];
    const float* cosb   = (const float*)d_in[1];
    const float* sinb   = (const float*)d_in[2];
    const float* w_attn = (const float*)d_in[3];
    const float* b_attn = (const float*)d_in[4];
    const float* w_proj = (const float*)d_in[5];
    const float* b_proj = (const float*)d_in[6];

    char* ws = (char*)d_ws;
    bf16_t*   xb  = (bf16_t*)(ws);                       //  8 MB: x bf16 (M,K)
    bf16_t*   waT = (bf16_t*)(ws + (size_t)(8 << 20));   //  6 MB: w_attn^T (N,K)
    bf16_t*   wpT = (bf16_t*)(ws + (size_t)(14 << 20));  //  2 MB: w_proj^T (N,K)
    bf16_t*   qb  = (bf16_t*)(ws + (size_t)(16 << 20));  //  8 MB: q bf16 (BH,T,HD), pre-scaled
    bf16_t*   kb  = (bf16_t*)(ws + (size_t)(24 << 20));  //  8 MB: k bf16 (BH,T,HD)
    _Float16* vtF = (_Float16*)(ws + (size_t)(32 << 20));//  8 MB: v^T f16 (BH,HD,T), key-permuted
    bf16_t*   yb  = (bf16_t*)(ws + (size_t)(40 << 20));  //  8 MB: attn out (M,C)

    convert_kernel<<<2048, 256, 0, stream>>>(x, xb);
    transpose_kernel<<<dim3(96, 32), 256, 0, stream>>>(w_attn, waT, Cdim, N3);
    transpose_kernel<<<dim3(32, 32), 256, 0, stream>>>(w_proj, wpT, Cdim, Cdim);
    gemm_qkv<<<dim3(24, 32), 256, 0, stream>>>(xb, waT, b_attn, cosb, sinb, qb, kb, vtF);
    attn_mfma<<<512, 256, 0, stream>>>(qb, kb, vtF, yb);
    gemm_proj<<<dim3(8, 32), 256, 0, stream>>>(yb, wpT, b_proj, (float*)d_out);
}